// Round 1
// baseline (308.019 us; speedup 1.0000x reference)
//
#include <hip/hip_runtime.h>

// Problem constants
#define V_N 256
#define T_N 256
#define K_N 36
#define L_N 32
#define D_N 1024
#define KP  48                    // K padded to multiple of 16 (zero rows)
#define MROWS (V_N * KP)          // 12288
#define NROWS (T_N * L_N)         // 8192
#define BM 128
#define BN 128
#define BK 64                     // bf16 elems per K-step
#define KSTEPS (D_N / BK)         // 16

typedef __attribute__((ext_vector_type(8))) short bf16x8;
typedef __attribute__((ext_vector_type(4))) float f32x4;

// fp32 -> bf16 RNE, branchless
__device__ __forceinline__ ushort f2bf(float x) {
  union { float f; unsigned int u; } c; c.f = x;
  unsigned int r = c.u + 0x7FFFu + ((c.u >> 16) & 1u);
  return (ushort)(r >> 16);
}

// ---------------- conversion kernel: fp32 -> padded bf16 workspace ----------
__global__ void cvt_pad(const float* __restrict__ imgs, const float* __restrict__ caps,
                        ushort* __restrict__ aws, ushort* __restrict__ bws) {
  const int AQ = MROWS * (D_N / 4);   // quads in padded A
  const int BQ = NROWS * (D_N / 4);
  const int total = AQ + BQ;
  for (int q = blockIdx.x * blockDim.x + threadIdx.x; q < total;
       q += gridDim.x * blockDim.x) {
    if (q < AQ) {
      int row = q >> 8;               // D/4 = 256 quads per row
      int c4  = q & 255;
      int v = row / KP, k = row - v * KP;
      float4 f = make_float4(0.f, 0.f, 0.f, 0.f);
      if (k < K_N)
        f = reinterpret_cast<const float4*>(imgs)[((v * K_N + k) << 8) + c4];
      ushort4 u; u.x = f2bf(f.x); u.y = f2bf(f.y); u.z = f2bf(f.z); u.w = f2bf(f.w);
      reinterpret_cast<ushort4*>(aws)[q] = u;
    } else {
      int qq = q - AQ;
      float4 f = reinterpret_cast<const float4*>(caps)[qq];
      ushort4 u; u.x = f2bf(f.x); u.y = f2bf(f.y); u.z = f2bf(f.z); u.w = f2bf(f.w);
      reinterpret_cast<ushort4*>(bws)[qq] = u;
    }
  }
}

// ---------------- fused GEMM + square + block-sum ---------------------------
// S = A*B^T over bf16, out[v,t] += sum of squares of the S-tile entries.
// LDS layout: row-major [rows][BK] bf16 (128B rows), 16B-chunk XOR swizzle
// byte ^= ((row&7)<<4) applied on BOTH the staging source address and the
// ds_read address (global_load_lds writes linearly).
template <int USE_WS>
__global__ __launch_bounds__(256) void gemm_sq(
    const ushort* __restrict__ aws, const ushort* __restrict__ bws,
    const float* __restrict__ imgs, const float* __restrict__ caps,
    float* __restrict__ out) {
  __shared__ ushort lds[BM * BK + BN * BK];  // 32 KiB
  ushort* ldsA = lds;
  ushort* ldsB = lds + BM * BK;

  const int NBM = MROWS / BM;            // 96
  const int nwg = NBM * (NROWS / BN);    // 6144 (divisible by 8)
  int orig = (int)blockIdx.x;
  int wg = (orig & 7) * (nwg >> 3) + (orig >> 3);   // bijective XCD swizzle
  int bm = wg % NBM;
  int bn = wg / NBM;
  const int row0 = bm * BM;
  const int col0 = bn * BN;

  const int tid  = (int)threadIdx.x;
  const int lane = tid & 63;
  const int wid  = tid >> 6;
  const int wr   = wid >> 1;   // 0..1 (64-row slab)
  const int wc   = wid & 1;    // 0..1 (64-col slab)

  f32x4 acc[4][4];
#pragma unroll
  for (int i = 0; i < 4; ++i)
#pragma unroll
    for (int j = 0; j < 4; ++j) acc[i][j] = (f32x4){0.f, 0.f, 0.f, 0.f};

  for (int kt = 0; kt < KSTEPS; ++kt) {
    if (USE_WS) {
      // 16B async loads straight to LDS, source address pre-swizzled
#pragma unroll
      for (int it = 0; it < 4; ++it) {
        int q = it * 256 + tid;            // chunk id, lane-contiguous per wave
        int r = q >> 3;                    // tile row
        int cb = (q & 7) << 4;             // byte col in 128B row
        int sw = cb ^ ((r & 7) << 4);
        const ushort* ga = aws + (size_t)(row0 + r) * D_N + kt * BK + (sw >> 1);
        __builtin_amdgcn_global_load_lds(
            (const __attribute__((address_space(1))) void*)ga,
            (__attribute__((address_space(3))) void*)(ldsA + q * 8), 16, 0, 0);
      }
#pragma unroll
      for (int it = 0; it < 4; ++it) {
        int q = it * 256 + tid;
        int r = q >> 3;
        int cb = (q & 7) << 4;
        int sw = cb ^ ((r & 7) << 4);
        const ushort* gb = bws + (size_t)(col0 + r) * D_N + kt * BK + (sw >> 1);
        __builtin_amdgcn_global_load_lds(
            (const __attribute__((address_space(1))) void*)gb,
            (__attribute__((address_space(3))) void*)(ldsB + q * 8), 16, 0, 0);
      }
    } else {
      // reg-staged fp32 -> bf16 fallback (no workspace dependency)
#pragma unroll
      for (int it = 0; it < 4; ++it) {
        int q = it * 256 + tid;
        int r = q >> 3;
        int cb = (q & 7) << 4;
        int sw = cb ^ ((r & 7) << 4);
        int gr = row0 + r;
        int v = gr / KP, kk = gr - v * KP;
        float4 f0 = make_float4(0.f, 0.f, 0.f, 0.f), f1 = f0;
        if (kk < K_N) {
          const float4* src = reinterpret_cast<const float4*>(
              imgs + (size_t)(v * K_N + kk) * D_N + kt * BK + (sw >> 1));
          f0 = src[0]; f1 = src[1];
        }
        union { ushort u[8]; int4 v4; } pk;
        pk.u[0] = f2bf(f0.x); pk.u[1] = f2bf(f0.y);
        pk.u[2] = f2bf(f0.z); pk.u[3] = f2bf(f0.w);
        pk.u[4] = f2bf(f1.x); pk.u[5] = f2bf(f1.y);
        pk.u[6] = f2bf(f1.z); pk.u[7] = f2bf(f1.w);
        *reinterpret_cast<int4*>(ldsA + q * 8) = pk.v4;
      }
#pragma unroll
      for (int it = 0; it < 4; ++it) {
        int q = it * 256 + tid;
        int r = q >> 3;
        int cb = (q & 7) << 4;
        int sw = cb ^ ((r & 7) << 4);
        int gr = col0 + r;
        const float4* src = reinterpret_cast<const float4*>(
            caps + (size_t)gr * D_N + kt * BK + (sw >> 1));
        float4 f0 = src[0], f1 = src[1];
        union { ushort u[8]; int4 v4; } pk;
        pk.u[0] = f2bf(f0.x); pk.u[1] = f2bf(f0.y);
        pk.u[2] = f2bf(f0.z); pk.u[3] = f2bf(f0.w);
        pk.u[4] = f2bf(f1.x); pk.u[5] = f2bf(f1.y);
        pk.u[6] = f2bf(f1.z); pk.u[7] = f2bf(f1.w);
        *reinterpret_cast<int4*>(ldsB + q * 8) = pk.v4;
      }
    }
    __syncthreads();

#pragma unroll
    for (int ks = 0; ks < 2; ++ks) {
      bf16x8 afr[4], bfr[4];
#pragma unroll
      for (int i = 0; i < 4; ++i) {
        int r = wr * 64 + i * 16 + (lane & 15);
        int kb = ks * 64 + ((lane >> 4) << 4);      // byte offset along K
        int sw = kb ^ ((r & 7) << 4);
        afr[i] = *reinterpret_cast<const bf16x8*>(ldsA + r * BK + (sw >> 1));
      }
#pragma unroll
      for (int j = 0; j < 4; ++j) {
        int r = wc * 64 + j * 16 + (lane & 15);
        int kb = ks * 64 + ((lane >> 4) << 4);
        int sw = kb ^ ((r & 7) << 4);
        bfr[j] = *reinterpret_cast<const bf16x8*>(ldsB + r * BK + (sw >> 1));
      }
#pragma unroll
      for (int i = 0; i < 4; ++i)
#pragma unroll
        for (int j = 0; j < 4; ++j)
          acc[i][j] = __builtin_amdgcn_mfma_f32_16x16x32_bf16(
              afr[i], bfr[j], acc[i][j], 0, 0, 0);
    }
    __syncthreads();
  }

  // Epilogue: each 16x16 fragment lies in exactly one (v,t) cell
  // (48 = 3*16 rows per v, 32 = 2*16 cols per t). Sum of squares -> atomicAdd.
#pragma unroll
  for (int i = 0; i < 4; ++i) {
#pragma unroll
    for (int j = 0; j < 4; ++j) {
      f32x4 a4 = acc[i][j];
      float s = a4[0] * a4[0] + a4[1] * a4[1] + a4[2] * a4[2] + a4[3] * a4[3];
#pragma unroll
      for (int off = 32; off > 0; off >>= 1) s += __shfl_xor(s, off, 64);
      if (lane == 0) {
        int grow = row0 + wr * 64 + i * 16;
        int gcol = col0 + wc * 64 + j * 16;
        atomicAdd(out + (grow / KP) * T_N + (gcol / L_N), s);
      }
    }
  }
}

extern "C" void kernel_launch(void* const* d_in, const int* in_sizes, int n_in,
                              void* d_out, int out_size, void* d_ws, size_t ws_size,
                              hipStream_t stream) {
  const float* imgs = (const float*)d_in[0];
  const float* caps = (const float*)d_in[1];
  float* out = (float*)d_out;

  hipMemsetAsync(d_out, 0, (size_t)V_N * T_N * sizeof(float), stream);

  const size_t need = (size_t)(MROWS + NROWS) * D_N * sizeof(ushort);  // ~42 MB
  const int nwg = (MROWS / BM) * (NROWS / BN);                         // 6144

  if (ws_size >= need) {
    ushort* aws = (ushort*)d_ws;
    ushort* bws = aws + (size_t)MROWS * D_N;
    cvt_pad<<<2048, 256, 0, stream>>>(imgs, caps, aws, bws);
    gemm_sq<1><<<nwg, 256, 0, stream>>>(aws, bws, imgs, caps, out);
  } else {
    gemm_sq<0><<<nwg, 256, 0, stream>>>(nullptr, nullptr, imgs, caps, out);
  }
}